// Round 3
// baseline (1008.447 us; speedup 1.0000x reference)
//
#include <hip/hip_runtime.h>
#include <math.h>

constexpr int Bb = 4, Nn = 2048, Dd = 2048, Ee = 8, Cbn = 512;
constexpr int Mm = Bb * Nn;          // 8192 tokens

typedef _Float16 half8 __attribute__((ext_vector_type(8)));
typedef _Float16 half4v __attribute__((ext_vector_type(4)));
typedef float floatx16 __attribute__((ext_vector_type(16)));

#define GLL16(g, l)                                                     \
  __builtin_amdgcn_global_load_lds(                                     \
      (const __attribute__((address_space(1))) void*)(g),               \
      (__attribute__((address_space(3))) void*)(l), 16, 0, 0)

// ---------------- split X fp32 -> fp16 hi + lo ------------------------------
__global__ __launch_bounds__(256) void split_x(const float* __restrict__ X,
                                               _Float16* __restrict__ hi,
                                               _Float16* __restrict__ lo) {
  int i = (blockIdx.x * 256 + threadIdx.x) * 4;
  float4 v = *(const float4*)(X + i);
  half4v h, l;
  h.x = (_Float16)v.x; l.x = (_Float16)(v.x - (float)h.x);
  h.y = (_Float16)v.y; l.y = (_Float16)(v.y - (float)h.y);
  h.z = (_Float16)v.z; l.z = (_Float16)(v.z - (float)h.z);
  h.w = (_Float16)v.w; l.w = (_Float16)(v.w - (float)h.w);
  *(half4v*)(hi + i) = h;
  *(half4v*)(lo + i) = l;
}

// ---------------- transpose + split W: [E,D,C] f32 -> WT[hi/lo][E*C][D] -----
__global__ __launch_bounds__(256) void transpose_w(const float* __restrict__ W,
                                                   _Float16* __restrict__ WThi,
                                                   _Float16* __restrict__ WTlo) {
  const int kt = blockIdx.x;  // 0..31
  const int ct = blockIdx.y;  // 0..7
  const int e = blockIdx.z;   // 0..7
  __shared__ _Float16 thi[64][68];
  __shared__ _Float16 tlo[64][68];
  const int tx = threadIdx.x & 15, ty = threadIdx.x >> 4;
  const float* src = W + ((size_t)(e * 2048 + kt * 64)) * 512 + ct * 64;
#pragma unroll
  for (int p = 0; p < 4; ++p) {
    int kk = ty + p * 16;
    float4 v = *(const float4*)(src + (size_t)kk * 512 + tx * 4);
    _Float16 h;
    h = (_Float16)v.x; thi[tx * 4 + 0][kk] = h; tlo[tx * 4 + 0][kk] = (_Float16)(v.x - (float)h);
    h = (_Float16)v.y; thi[tx * 4 + 1][kk] = h; tlo[tx * 4 + 1][kk] = (_Float16)(v.y - (float)h);
    h = (_Float16)v.z; thi[tx * 4 + 2][kk] = h; tlo[tx * 4 + 2][kk] = (_Float16)(v.z - (float)h);
    h = (_Float16)v.w; thi[tx * 4 + 3][kk] = h; tlo[tx * 4 + 3][kk] = (_Float16)(v.w - (float)h);
  }
  __syncthreads();
  _Float16* dh = WThi + ((size_t)(e * 512 + ct * 64)) * 2048 + kt * 64;
  _Float16* dl = WTlo + ((size_t)(e * 512 + ct * 64)) * 2048 + kt * 64;
#pragma unroll
  for (int p = 0; p < 4; ++p) {
    int cc = ty + p * 16;
    half4v h, l;
    h.x = thi[cc][tx * 4 + 0]; l.x = tlo[cc][tx * 4 + 0];
    h.y = thi[cc][tx * 4 + 1]; l.y = tlo[cc][tx * 4 + 1];
    h.z = thi[cc][tx * 4 + 2]; l.z = tlo[cc][tx * 4 + 2];
    h.w = thi[cc][tx * 4 + 3]; l.w = tlo[cc][tx * 4 + 3];
    *(half4v*)(dh + (size_t)cc * 2048 + tx * 4) = h;
    *(half4v*)(dl + (size_t)cc * 2048 + tx * 4) = l;
  }
}

// ---------------- MFMA GEMM + fused square-reduce (double-buffered) ---------
__global__ __launch_bounds__(256) void gemm_mfma(const _Float16* __restrict__ Xhi,
                                                 const _Float16* __restrict__ Xlo,
                                                 const _Float16* __restrict__ WThi,
                                                 const _Float16* __restrict__ WTlo,
                                                 float* __restrict__ partial) {
  const int mtile = blockIdx.x;  // 64
  const int ntile = blockIdx.y;  // 32
  const int tid = threadIdx.x;
  const int wave = tid >> 6, lane = tid & 63;
  const int wm = wave >> 1, wn = wave & 1;
  const int h = lane >> 5;

  __shared__ __align__(16) char lds[2][32768];
  // region offsets within a buffer: Ahi 0, Alo 8192, Bhi 16384, Blo 24576

  // staging addressing (XOR chunk swizzle, wave-uniform base + lane*16)
  const int lr = lane >> 2;
  const int cpos = lane & 3;
  const int cg = cpos ^ ((lr >> 1) & 3);
  const int r0 = wave * 32 + lr;
  const int r1 = r0 + 16;
  const _Float16* xh0 = Xhi + (size_t)(mtile * 128 + r0) * 2048 + cg * 8;
  const _Float16* xh1 = Xhi + (size_t)(mtile * 128 + r1) * 2048 + cg * 8;
  const _Float16* xl0 = Xlo + (size_t)(mtile * 128 + r0) * 2048 + cg * 8;
  const _Float16* xl1 = Xlo + (size_t)(mtile * 128 + r1) * 2048 + cg * 8;
  const _Float16* wh0 = WThi + (size_t)(ntile * 128 + r0) * 2048 + cg * 8;
  const _Float16* wh1 = WThi + (size_t)(ntile * 128 + r1) * 2048 + cg * 8;
  const _Float16* wl0 = WTlo + (size_t)(ntile * 128 + r0) * 2048 + cg * 8;
  const _Float16* wl1 = WTlo + (size_t)(ntile * 128 + r1) * 2048 + cg * 8;
  const int lq0 = wave * 2048;
  const int lq1 = lq0 + 1024;

  // fragment read offsets (bytes within a tile region)
  const int rA0 = wm * 64 + (lane & 31);
  const int rA1 = rA0 + 32;
  const int rB0 = wn * 64 + (lane & 31);
  const int rB1 = rB0 + 32;
  auto foff = [&](int r, int s) {
    return r * 64 + (((s * 2 + h) ^ ((r >> 1) & 3)) << 4);
  };
  const int oA0[2] = {foff(rA0, 0), foff(rA0, 1)};
  const int oA1[2] = {foff(rA1, 0), foff(rA1, 1)};
  const int oB0[2] = {foff(rB0, 0), foff(rB0, 1)};
  const int oB1[2] = {foff(rB1, 0), foff(rB1, 1)};

  floatx16 acc00 = {}, acc01 = {}, acc10 = {}, acc11 = {};

  auto issue = [&](int kt, int buf) {
    const int k0 = kt * 32;
    char* L = lds[buf];
    GLL16(xh0 + k0, L + lq0);
    GLL16(xh1 + k0, L + lq1);
    GLL16(xl0 + k0, L + 8192 + lq0);
    GLL16(xl1 + k0, L + 8192 + lq1);
    GLL16(wh0 + k0, L + 16384 + lq0);
    GLL16(wh1 + k0, L + 16384 + lq1);
    GLL16(wl0 + k0, L + 24576 + lq0);
    GLL16(wl1 + k0, L + 24576 + lq1);
  };

  issue(0, 0);
  int p = 0;
  for (int kt = 0; kt < 64; ++kt) {
    __syncthreads();  // drains vmcnt -> buf[p] valid; prev reads done
    if (kt < 63) issue(kt + 1, p ^ 1);
    const char* Ahi = lds[p];
    const char* Alo = Ahi + 8192;
    const char* Bhi = Ahi + 16384;
    const char* Blo = Ahi + 24576;
#pragma unroll
    for (int s = 0; s < 2; ++s) {
      half8 ah0 = *(const half8*)(Ahi + oA0[s]);
      half8 ah1 = *(const half8*)(Ahi + oA1[s]);
      half8 al0 = *(const half8*)(Alo + oA0[s]);
      half8 al1 = *(const half8*)(Alo + oA1[s]);
      half8 bh0 = *(const half8*)(Bhi + oB0[s]);
      half8 bh1 = *(const half8*)(Bhi + oB1[s]);
      half8 bl0 = *(const half8*)(Blo + oB0[s]);
      half8 bl1 = *(const half8*)(Blo + oB1[s]);
      acc00 = __builtin_amdgcn_mfma_f32_32x32x16_f16(ah0, bh0, acc00, 0, 0, 0);
      acc00 = __builtin_amdgcn_mfma_f32_32x32x16_f16(ah0, bl0, acc00, 0, 0, 0);
      acc00 = __builtin_amdgcn_mfma_f32_32x32x16_f16(al0, bh0, acc00, 0, 0, 0);
      acc01 = __builtin_amdgcn_mfma_f32_32x32x16_f16(ah0, bh1, acc01, 0, 0, 0);
      acc01 = __builtin_amdgcn_mfma_f32_32x32x16_f16(ah0, bl1, acc01, 0, 0, 0);
      acc01 = __builtin_amdgcn_mfma_f32_32x32x16_f16(al0, bh1, acc01, 0, 0, 0);
      acc10 = __builtin_amdgcn_mfma_f32_32x32x16_f16(ah1, bh0, acc10, 0, 0, 0);
      acc10 = __builtin_amdgcn_mfma_f32_32x32x16_f16(ah1, bl0, acc10, 0, 0, 0);
      acc10 = __builtin_amdgcn_mfma_f32_32x32x16_f16(al1, bh0, acc10, 0, 0, 0);
      acc11 = __builtin_amdgcn_mfma_f32_32x32x16_f16(ah1, bh1, acc11, 0, 0, 0);
      acc11 = __builtin_amdgcn_mfma_f32_32x32x16_f16(ah1, bl1, acc11, 0, 0, 0);
      acc11 = __builtin_amdgcn_mfma_f32_32x32x16_f16(al1, bh1, acc11, 0, 0, 0);
    }
    p ^= 1;
  }

  // epilogue: per-row sum of squares over this wave's 64 cols
  float myv = 0.f;
#pragma unroll
  for (int i = 0; i < 2; ++i) {
    const floatx16& c0 = i ? acc10 : acc00;
    const floatx16& c1 = i ? acc11 : acc01;
#pragma unroll
    for (int reg = 0; reg < 16; ++reg) {
      float v = c0[reg] * c0[reg] + c1[reg] * c1[reg];
#pragma unroll
      for (int m = 1; m <= 16; m <<= 1) v += __shfl_xor(v, m, 64);
      if ((lane & 31) == i * 16 + reg) myv = v;
    }
  }
  {
    const int i = (lane & 31) >> 4;
    const int reg = lane & 15;
    const int row = i * 32 + (reg & 3) + 8 * (reg >> 2) + 4 * h;
    const int token = mtile * 128 + wm * 64 + row;
    const int slice = ntile * 2 + wn;  // e*8+u
    partial[(size_t)slice * Mm + token] = myv;
  }
}

// ---------------- fused routing: softmax+top2+capacity scan (per batch) -----
__global__ __launch_bounds__(256) void scan_route(const float* __restrict__ partial,
                                                  int* __restrict__ ig,
                                                  float* __restrict__ p1g,
                                                  float* __restrict__ p2g,
                                                  int* __restrict__ prios) {
  const int b = blockIdx.x;
  const int tid = threadIdx.x;
  __shared__ unsigned char sI1[Nn];
  __shared__ unsigned char sI2[Nn];
  __shared__ int cnts[256][8];

  // phase 1: routing decisions for this batch's 2048 tokens
  for (int i = 0; i < 8; ++i) {
    const int tl = i * 256 + tid;
    const int t = b * Nn + tl;
    float l[Ee];
    float mx = -1e30f;
#pragma unroll
    for (int e = 0; e < Ee; ++e) {
      float s = 0.f;
#pragma unroll
      for (int u = 0; u < 8; ++u) s += partial[(size_t)(e * 8 + u) * Mm + t];
      l[e] = sqrtf(s);
      mx = fmaxf(mx, l[e]);
    }
    float sum = 0.f, pe[Ee];
#pragma unroll
    for (int e = 0; e < Ee; ++e) {
      pe[e] = expf(l[e] - mx);
      sum += pe[e];
    }
    float inv = 1.f / sum;
    int i1 = 0;
    float b1 = l[0];
#pragma unroll
    for (int e = 1; e < Ee; ++e)
      if (l[e] > b1) { b1 = l[e]; i1 = e; }
    int i2 = -1;
    float b2 = -1e30f;
#pragma unroll
    for (int e = 0; e < Ee; ++e)
      if (e != i1 && l[e] > b2) { b2 = l[e]; i2 = e; }
    sI1[tl] = (unsigned char)i1;
    sI2[tl] = (unsigned char)i2;
    ig[t] = i1 | (i2 << 8);
    p1g[t] = pe[i1] * inv;
    p2g[t] = pe[i2] * inv;
  }
  __syncthreads();

  // phase 2: capacity priority scan over 4096 ordered positions
  int cnt[8] = {0, 0, 0, 0, 0, 0, 0, 0};
  int eloc[16];
  const int base_p = tid * 16;
#pragma unroll
  for (int i = 0; i < 16; ++i) {
    int pp = base_p + i;
    int k = pp >> 11;
    int n = pp & (Nn - 1);
    int e = k == 0 ? (int)sI1[n] : (int)sI2[n];
    eloc[i] = e;
    cnt[e]++;
  }
#pragma unroll
  for (int e = 0; e < 8; ++e) cnts[tid][e] = cnt[e];
  __syncthreads();
  if (tid < 8) {
    int run = 0;
    for (int i = 0; i < 256; ++i) {
      int v = cnts[i][tid];
      cnts[i][tid] = run;
      run += v;
    }
  }
  __syncthreads();
  int base[8];
#pragma unroll
  for (int e = 0; e < 8; ++e) base[e] = cnts[tid][e];
#pragma unroll
  for (int i = 0; i < 16; ++i) {
    int e = eloc[i];
    prios[b * 2 * Nn + base_p + i] = base[e]++;
  }
}

// ---------------- fused zero + scatter: write each row exactly once ---------
__global__ __launch_bounds__(256) void out_kernel(const int* __restrict__ ig,
                                                  const float* __restrict__ p1g,
                                                  const float* __restrict__ p2g,
                                                  const int* __restrict__ prios,
                                                  float* __restrict__ out, int cap) {
  const int t = blockIdx.x;  // 8192 token-blocks
  const int tid = threadIdx.x;
  const int b = t >> 11, n = t & (Nn - 1);
  const int pair = ig[t];
  const int e1 = pair & 0xff, e2 = (pair >> 8) & 0xff;
  const int q1 = prios[b * 2 * Nn + n];
  const int q2 = prios[b * 2 * Nn + Nn + n];
  const float v1 = p1g[t], v2 = p2g[t];
  const int g1 = (q1 < cap) ? e1 * cap + q1 : -1;
  const int g2 = (q2 < cap) ? e2 * cap + q2 : -1;
  const int row4 = Ee * cap / 4;  // 1280 float4 per row
  float4* drow = (float4*)out + (size_t)t * row4;
  float4* crow = drow + (size_t)Mm * row4;
  for (int f = tid; f < row4; f += 256) {
    float4 d = make_float4(0.f, 0.f, 0.f, 0.f);
    float4 c = make_float4(0.f, 0.f, 0.f, 0.f);
    const int base = f * 4;
    if (g1 >= base && g1 < base + 4) {
      ((float*)&d)[g1 - base] = 1.f;
      ((float*)&c)[g1 - base] = v1;
    }
    if (g2 >= base && g2 < base + 4) {
      ((float*)&d)[g2 - base] = 1.f;
      ((float*)&c)[g2 - base] = v2;
    }
    drow[f] = d;
    crow[f] = c;
  }
}

extern "C" void kernel_launch(void* const* d_in, const int* in_sizes, int n_in,
                              void* d_out, int out_size, void* d_ws, size_t ws_size,
                              hipStream_t stream) {
  const float* X = (const float*)d_in[0];
  const float* W = (const float*)d_in[1];
  float* out = (float*)d_out;
  const int cap = out_size / (2 * Bb * Nn * Ee);  // 640

  char* ws = (char*)d_ws;
  _Float16* Xhi = (_Float16*)ws;                   // 32 MB
  _Float16* Xlo = (_Float16*)(ws + 33554432ull);   // 32 MB
  _Float16* WThi = (_Float16*)(ws + 67108864ull);  // 16 MB
  _Float16* WTlo = (_Float16*)(ws + 83886080ull);  // 16 MB
  float* partial = (float*)(ws + 100663296ull);    // 64*8192*4 = 2 MB
  int* ig = (int*)(ws + 102760448ull);
  float* p1g = (float*)(ig + Mm);
  float* p2g = p1g + Mm;
  int* prios = (int*)(p2g + Mm);

  split_x<<<(Mm * Dd) / 1024, 256, 0, stream>>>(X, Xhi, Xlo);
  transpose_w<<<dim3(32, 8, 8), 256, 0, stream>>>(W, WThi, WTlo);
  gemm_mfma<<<dim3(64, 32), 256, 0, stream>>>(Xhi, Xlo, WThi, WTlo, partial);
  scan_route<<<Bb, 256, 0, stream>>>(partial, ig, p1g, p2g, prios);
  out_kernel<<<Mm, 256, 0, stream>>>(ig, p1g, p2g, prios, out, cap);
}

// Round 4
// 818.937 us; speedup vs baseline: 1.2314x; 1.2314x over previous
//
#include <hip/hip_runtime.h>
#include <math.h>

constexpr int Bb = 4, Nn = 2048, Dd = 2048, Ee = 8, Cbn = 512;
constexpr int Mm = Bb * Nn;          // 8192 tokens

typedef _Float16 half8 __attribute__((ext_vector_type(8)));
typedef float floatx16 __attribute__((ext_vector_type(16)));

#define GLL16(g, l)                                                     \
  __builtin_amdgcn_global_load_lds(                                     \
      (const __attribute__((address_space(1))) void*)(g),               \
      (__attribute__((address_space(3))) void*)(l), 16, 0, 0)

// ---------------- split X fp32 -> fp16 hi + lo (wide: 32B in, 2x16B out) ----
__global__ __launch_bounds__(256) void split_x(const float* __restrict__ X,
                                               _Float16* __restrict__ hi,
                                               _Float16* __restrict__ lo) {
  const int i = (blockIdx.x * 256 + threadIdx.x) * 8;
  float4 v0 = *(const float4*)(X + i);
  float4 v1 = *(const float4*)(X + i + 4);
  half8 h, l;
  h[0] = (_Float16)v0.x; l[0] = (_Float16)(v0.x - (float)h[0]);
  h[1] = (_Float16)v0.y; l[1] = (_Float16)(v0.y - (float)h[1]);
  h[2] = (_Float16)v0.z; l[2] = (_Float16)(v0.z - (float)h[2]);
  h[3] = (_Float16)v0.w; l[3] = (_Float16)(v0.w - (float)h[3]);
  h[4] = (_Float16)v1.x; l[4] = (_Float16)(v1.x - (float)h[4]);
  h[5] = (_Float16)v1.y; l[5] = (_Float16)(v1.y - (float)h[5]);
  h[6] = (_Float16)v1.z; l[6] = (_Float16)(v1.z - (float)h[6]);
  h[7] = (_Float16)v1.w; l[7] = (_Float16)(v1.w - (float)h[7]);
  *(half8*)(hi + i) = h;
  *(half8*)(lo + i) = l;
}

// ---------------- transpose + split W: [E,D,C] f32 -> WT[hi/lo][E*C][D] -----
// 64k x 64c tile per block; 16B half8 global writes.
__global__ __launch_bounds__(256) void transpose_w(const float* __restrict__ W,
                                                   _Float16* __restrict__ WThi,
                                                   _Float16* __restrict__ WTlo) {
  const int kt = blockIdx.x;  // 0..31
  const int ct = blockIdx.y;  // 0..7
  const int e = blockIdx.z;   // 0..7
  __shared__ _Float16 thi[64][72];  // [c][k], 144B row stride (16B aligned)
  __shared__ _Float16 tlo[64][72];
  const int tx = threadIdx.x & 15, ty = threadIdx.x >> 4;
  const float* src = W + ((size_t)(e * 2048 + kt * 64)) * 512 + ct * 64;
#pragma unroll
  for (int p = 0; p < 4; ++p) {
    int kk = ty + p * 16;
    float4 v = *(const float4*)(src + (size_t)kk * 512 + tx * 4);
    _Float16 h;
    h = (_Float16)v.x; thi[tx * 4 + 0][kk] = h; tlo[tx * 4 + 0][kk] = (_Float16)(v.x - (float)h);
    h = (_Float16)v.y; thi[tx * 4 + 1][kk] = h; tlo[tx * 4 + 1][kk] = (_Float16)(v.y - (float)h);
    h = (_Float16)v.z; thi[tx * 4 + 2][kk] = h; tlo[tx * 4 + 2][kk] = (_Float16)(v.z - (float)h);
    h = (_Float16)v.w; thi[tx * 4 + 3][kk] = h; tlo[tx * 4 + 3][kk] = (_Float16)(v.w - (float)h);
  }
  __syncthreads();
  const int rr = threadIdx.x >> 3;  // 0..31 (c row)
  const int ch = threadIdx.x & 7;   // 16B chunk within 128B row
  _Float16* dh = WThi + ((size_t)(e * 512 + ct * 64)) * 2048 + kt * 64;
  _Float16* dl = WTlo + ((size_t)(e * 512 + ct * 64)) * 2048 + kt * 64;
#pragma unroll
  for (int p = 0; p < 2; ++p) {
    int cc = rr + p * 32;
    *(half8*)(dh + (size_t)cc * 2048 + ch * 8) = *(const half8*)(&thi[cc][ch * 8]);
    *(half8*)(dl + (size_t)cc * 2048 + ch * 8) = *(const half8*)(&tlo[cc][ch * 8]);
  }
}

// ---------------- MFMA GEMM + fused square-reduce (single-buffer + swizzle) -
__global__ __launch_bounds__(256) void gemm_mfma(const _Float16* __restrict__ Xhi,
                                                 const _Float16* __restrict__ Xlo,
                                                 const _Float16* __restrict__ WThi,
                                                 const _Float16* __restrict__ WTlo,
                                                 float* __restrict__ partial) {
  // 16x16 supertile swizzle: concurrent blocks share a 16-mtile x 16-ntile
  // region (16MB A + 16MB B footprint); ntile fastest -> per-XCD B slice 2MB.
  const int bid = blockIdx.x;
  const int st = bid >> 8;        // 0..7
  const int stm = st & 3;         // 4 supertiles along m
  const int stn = st >> 2;        // 2 supertiles along n
  const int li = bid & 255;
  const int mtile = stm * 16 + (li >> 4);
  const int ntile = stn * 16 + (li & 15);

  const int tid = threadIdx.x;
  const int wave = tid >> 6, lane = tid & 63;
  const int wm = wave >> 1, wn = wave & 1;
  const int h = lane >> 5;

  __shared__ __align__(16) char lds[32768];
  char* ldsAhi = lds;
  char* ldsAlo = lds + 8192;
  char* ldsBhi = lds + 16384;
  char* ldsBlo = lds + 24576;

  // staging addressing (XOR chunk swizzle; DMA dest = wave base + lane*16)
  const int lr = lane >> 2;
  const int cpos = lane & 3;
  const int cg = cpos ^ ((lr >> 1) & 3);
  const int r0 = wave * 32 + lr;
  const int r1 = r0 + 16;
  const _Float16* xh0 = Xhi + (size_t)(mtile * 128 + r0) * 2048 + cg * 8;
  const _Float16* xh1 = Xhi + (size_t)(mtile * 128 + r1) * 2048 + cg * 8;
  const _Float16* xl0 = Xlo + (size_t)(mtile * 128 + r0) * 2048 + cg * 8;
  const _Float16* xl1 = Xlo + (size_t)(mtile * 128 + r1) * 2048 + cg * 8;
  const _Float16* wh0 = WThi + (size_t)(ntile * 128 + r0) * 2048 + cg * 8;
  const _Float16* wh1 = WThi + (size_t)(ntile * 128 + r1) * 2048 + cg * 8;
  const _Float16* wl0 = WTlo + (size_t)(ntile * 128 + r0) * 2048 + cg * 8;
  const _Float16* wl1 = WTlo + (size_t)(ntile * 128 + r1) * 2048 + cg * 8;
  const int lq0 = wave * 2048;
  const int lq1 = lq0 + 1024;

  // fragment read offsets (bytes within a tile region)
  const int rA0 = wm * 64 + (lane & 31);
  const int rA1 = rA0 + 32;
  const int rB0 = wn * 64 + (lane & 31);
  const int rB1 = rB0 + 32;
  auto foff = [&](int r, int s) {
    return r * 64 + (((s * 2 + h) ^ ((r >> 1) & 3)) << 4);
  };
  const int oA0[2] = {foff(rA0, 0), foff(rA0, 1)};
  const int oA1[2] = {foff(rA1, 0), foff(rA1, 1)};
  const int oB0[2] = {foff(rB0, 0), foff(rB0, 1)};
  const int oB1[2] = {foff(rB1, 0), foff(rB1, 1)};

  floatx16 acc00 = {}, acc01 = {}, acc10 = {}, acc11 = {};

  for (int kt = 0; kt < 64; ++kt) {
    const int k0 = kt * 32;
    GLL16(xh0 + k0, ldsAhi + lq0);
    GLL16(xh1 + k0, ldsAhi + lq1);
    GLL16(xl0 + k0, ldsAlo + lq0);
    GLL16(xl1 + k0, ldsAlo + lq1);
    GLL16(wh0 + k0, ldsBhi + lq0);
    GLL16(wh1 + k0, ldsBhi + lq1);
    GLL16(wl0 + k0, ldsBlo + lq0);
    GLL16(wl1 + k0, ldsBlo + lq1);
    __syncthreads();  // drains vmcnt -> LDS tiles valid
#pragma unroll
    for (int s = 0; s < 2; ++s) {
      half8 ah0 = *(const half8*)(ldsAhi + oA0[s]);
      half8 ah1 = *(const half8*)(ldsAhi + oA1[s]);
      half8 al0 = *(const half8*)(ldsAlo + oA0[s]);
      half8 al1 = *(const half8*)(ldsAlo + oA1[s]);
      half8 bh0 = *(const half8*)(ldsBhi + oB0[s]);
      half8 bh1 = *(const half8*)(ldsBhi + oB1[s]);
      half8 bl0 = *(const half8*)(ldsBlo + oB0[s]);
      half8 bl1 = *(const half8*)(ldsBlo + oB1[s]);
      acc00 = __builtin_amdgcn_mfma_f32_32x32x16_f16(ah0, bh0, acc00, 0, 0, 0);
      acc00 = __builtin_amdgcn_mfma_f32_32x32x16_f16(ah0, bl0, acc00, 0, 0, 0);
      acc00 = __builtin_amdgcn_mfma_f32_32x32x16_f16(al0, bh0, acc00, 0, 0, 0);
      acc01 = __builtin_amdgcn_mfma_f32_32x32x16_f16(ah0, bh1, acc01, 0, 0, 0);
      acc01 = __builtin_amdgcn_mfma_f32_32x32x16_f16(ah0, bl1, acc01, 0, 0, 0);
      acc01 = __builtin_amdgcn_mfma_f32_32x32x16_f16(al0, bh1, acc01, 0, 0, 0);
      acc10 = __builtin_amdgcn_mfma_f32_32x32x16_f16(ah1, bh0, acc10, 0, 0, 0);
      acc10 = __builtin_amdgcn_mfma_f32_32x32x16_f16(ah1, bl0, acc10, 0, 0, 0);
      acc10 = __builtin_amdgcn_mfma_f32_32x32x16_f16(al1, bh0, acc10, 0, 0, 0);
      acc11 = __builtin_amdgcn_mfma_f32_32x32x16_f16(ah1, bh1, acc11, 0, 0, 0);
      acc11 = __builtin_amdgcn_mfma_f32_32x32x16_f16(ah1, bl1, acc11, 0, 0, 0);
      acc11 = __builtin_amdgcn_mfma_f32_32x32x16_f16(al1, bh1, acc11, 0, 0, 0);
    }
    __syncthreads();
  }

  // epilogue: per-row sum of squares over this wave's 64 cols
  float myv = 0.f;
#pragma unroll
  for (int i = 0; i < 2; ++i) {
    const floatx16& c0 = i ? acc10 : acc00;
    const floatx16& c1 = i ? acc11 : acc01;
#pragma unroll
    for (int reg = 0; reg < 16; ++reg) {
      float v = c0[reg] * c0[reg] + c1[reg] * c1[reg];
#pragma unroll
      for (int m = 1; m <= 16; m <<= 1) v += __shfl_xor(v, m, 64);
      if ((lane & 31) == i * 16 + reg) myv = v;
    }
  }
  {
    const int i = (lane & 31) >> 4;
    const int reg = lane & 15;
    const int row = i * 32 + (reg & 3) + 8 * (reg >> 2) + 4 * h;
    const int token = mtile * 128 + wm * 64 + row;
    const int slice = ntile * 2 + wn;  // e*8+u
    partial[(size_t)slice * Mm + token] = myv;
  }
}

// ---------------- softmax + top-2 per token ---------------------------------
__global__ void route_kernel(const float* __restrict__ partial,
                             int* __restrict__ idx1, int* __restrict__ idx2,
                             float* __restrict__ p1, float* __restrict__ p2) {
  int t = blockIdx.x * blockDim.x + threadIdx.x;
  if (t >= Mm) return;
  float l[Ee];
  float mx = -1e30f;
#pragma unroll
  for (int e = 0; e < Ee; ++e) {
    float s = 0.f;
#pragma unroll
    for (int u = 0; u < 8; ++u) s += partial[(size_t)(e * 8 + u) * Mm + t];
    l[e] = sqrtf(s);
    mx = fmaxf(mx, l[e]);
  }
  float p[Ee];
  float s = 0.f;
#pragma unroll
  for (int e = 0; e < Ee; ++e) {
    p[e] = expf(l[e] - mx);
    s += p[e];
  }
  float inv = 1.f / s;
  int i1 = 0;
  float b1 = l[0];
#pragma unroll
  for (int e = 1; e < Ee; ++e)
    if (l[e] > b1) { b1 = l[e]; i1 = e; }
  int i2 = -1;
  float b2 = -1e30f;
#pragma unroll
  for (int e = 0; e < Ee; ++e)
    if (e != i1 && l[e] > b2) { b2 = l[e]; i2 = e; }
  idx1[t] = i1;
  idx2[t] = i2;
  p1[t] = p[i1] * inv;
  p2[t] = p[i2] * inv;
}

// ---------------- per-batch capacity priority scan --------------------------
__global__ void scan_kernel(const int* __restrict__ idx1,
                            const int* __restrict__ idx2,
                            int* __restrict__ prios) {
  const int b = blockIdx.x;
  const int tid = threadIdx.x;
  __shared__ int cnts[256][8];
  int cnt[8] = {0, 0, 0, 0, 0, 0, 0, 0};
  int eloc[16];
  const int base_p = tid * 16;
#pragma unroll
  for (int i = 0; i < 16; ++i) {
    int p = base_p + i;
    int k = p >> 11;
    int n = p & (Nn - 1);
    int e = (k == 0 ? idx1 : idx2)[b * Nn + n];
    eloc[i] = e;
    cnt[e]++;
  }
#pragma unroll
  for (int e = 0; e < 8; ++e) cnts[tid][e] = cnt[e];
  __syncthreads();
  if (tid < 8) {
    int run = 0;
    for (int i = 0; i < 256; ++i) {
      int v = cnts[i][tid];
      cnts[i][tid] = run;
      run += v;
    }
  }
  __syncthreads();
  int base[8];
#pragma unroll
  for (int e = 0; e < 8; ++e) base[e] = cnts[tid][e];
#pragma unroll
  for (int i = 0; i < 16; ++i) {
    int e = eloc[i];
    prios[b * 2 * Nn + base_p + i] = base[e]++;
  }
}

// ---------------- zero output ------------------------------------------------
__global__ void zero_kernel(float4* __restrict__ out, int n4) {
  int i = blockIdx.x * blockDim.x + threadIdx.x;
  if (i < n4) out[i] = make_float4(0.f, 0.f, 0.f, 0.f);
}

// ---------------- scatter dispatch/combine ----------------------------------
__global__ void scatter_kernel(const int* __restrict__ idx1,
                               const int* __restrict__ idx2,
                               const float* __restrict__ p1,
                               const float* __restrict__ p2,
                               const int* __restrict__ prios,
                               float* __restrict__ out, int cap) {
  int t = blockIdx.x * blockDim.x + threadIdx.x;
  if (t >= Mm) return;
  int b = t >> 11;
  int n = t & (Nn - 1);
  size_t disp = (size_t)t * Ee * cap;
  size_t comb = disp + (size_t)Mm * Ee * cap;
  {
    int e = idx1[t];
    int p = prios[b * 2 * Nn + n];
    if (p < cap) {
      out[disp + (size_t)e * cap + p] = 1.f;
      out[comb + (size_t)e * cap + p] = p1[t];
    }
  }
  {
    int e = idx2[t];
    int p = prios[b * 2 * Nn + Nn + n];
    if (p < cap) {
      out[disp + (size_t)e * cap + p] = 1.f;
      out[comb + (size_t)e * cap + p] = p2[t];
    }
  }
}

extern "C" void kernel_launch(void* const* d_in, const int* in_sizes, int n_in,
                              void* d_out, int out_size, void* d_ws, size_t ws_size,
                              hipStream_t stream) {
  const float* X = (const float*)d_in[0];
  const float* W = (const float*)d_in[1];
  float* out = (float*)d_out;
  const int cap = out_size / (2 * Bb * Nn * Ee);  // 640

  char* ws = (char*)d_ws;
  _Float16* Xhi = (_Float16*)ws;                   // 32 MB
  _Float16* Xlo = (_Float16*)(ws + 33554432ull);   // 32 MB
  _Float16* WThi = (_Float16*)(ws + 67108864ull);  // 16 MB
  _Float16* WTlo = (_Float16*)(ws + 83886080ull);  // 16 MB
  float* partial = (float*)(ws + 100663296ull);    // 2 MB
  int* idx1 = (int*)(ws + 102760448ull);
  int* idx2 = idx1 + Mm;
  float* p1 = (float*)(idx2 + Mm);
  float* p2 = p1 + Mm;
  int* prios = (int*)(p2 + Mm);

  split_x<<<(Mm * Dd) / 2048, 256, 0, stream>>>(X, Xhi, Xlo);
  transpose_w<<<dim3(32, 8, 8), 256, 0, stream>>>(W, WThi, WTlo);
  gemm_mfma<<<2048, 256, 0, stream>>>(Xhi, Xlo, WThi, WTlo, partial);
  route_kernel<<<Mm / 256, 256, 0, stream>>>(partial, idx1, idx2, p1, p2);
  scan_kernel<<<Bb, 256, 0, stream>>>(idx1, idx2, prios);
  const int n4 = out_size / 4;
  zero_kernel<<<(n4 + 255) / 256, 256, 0, stream>>>((float4*)out, n4);
  scatter_kernel<<<Mm / 256, 256, 0, stream>>>(idx1, idx2, p1, p2, prios, out, cap);
}

// Round 5
// 808.906 us; speedup vs baseline: 1.2467x; 1.0124x over previous
//
#include <hip/hip_runtime.h>
#include <math.h>

constexpr int Bb = 4, Nn = 2048, Dd = 2048, Ee = 8, Cbn = 512;
constexpr int Mm = Bb * Nn;          // 8192 tokens

typedef _Float16 half8 __attribute__((ext_vector_type(8)));
typedef float floatx16 __attribute__((ext_vector_type(16)));

#define GLL16(g, l)                                                     \
  __builtin_amdgcn_global_load_lds(                                     \
      (const __attribute__((address_space(1))) void*)(g),               \
      (__attribute__((address_space(3))) void*)(l), 16, 0, 0)

// ---------------- transpose + split W: [E,D,C] f32 -> WT[hi/lo][E*C][D] -----
__global__ __launch_bounds__(256) void transpose_w(const float* __restrict__ W,
                                                   _Float16* __restrict__ WThi,
                                                   _Float16* __restrict__ WTlo) {
  const int kt = blockIdx.x;  // 0..31
  const int ct = blockIdx.y;  // 0..7
  const int e = blockIdx.z;   // 0..7
  __shared__ _Float16 thi[64][72];  // [c][k]
  __shared__ _Float16 tlo[64][72];
  const int tx = threadIdx.x & 15, ty = threadIdx.x >> 4;
  const float* src = W + ((size_t)(e * 2048 + kt * 64)) * 512 + ct * 64;
#pragma unroll
  for (int p = 0; p < 4; ++p) {
    int kk = ty + p * 16;
    float4 v = *(const float4*)(src + (size_t)kk * 512 + tx * 4);
    _Float16 h;
    h = (_Float16)v.x; thi[tx * 4 + 0][kk] = h; tlo[tx * 4 + 0][kk] = (_Float16)(v.x - (float)h);
    h = (_Float16)v.y; thi[tx * 4 + 1][kk] = h; tlo[tx * 4 + 1][kk] = (_Float16)(v.y - (float)h);
    h = (_Float16)v.z; thi[tx * 4 + 2][kk] = h; tlo[tx * 4 + 2][kk] = (_Float16)(v.z - (float)h);
    h = (_Float16)v.w; thi[tx * 4 + 3][kk] = h; tlo[tx * 4 + 3][kk] = (_Float16)(v.w - (float)h);
  }
  __syncthreads();
  const int rr = threadIdx.x >> 3;  // 0..31
  const int ch = threadIdx.x & 7;   // 16B chunk
  _Float16* dh = WThi + ((size_t)(e * 512 + ct * 64)) * 2048 + kt * 64;
  _Float16* dl = WTlo + ((size_t)(e * 512 + ct * 64)) * 2048 + kt * 64;
#pragma unroll
  for (int p = 0; p < 2; ++p) {
    int cc = rr + p * 32;
    *(half8*)(dh + (size_t)cc * 2048 + ch * 8) = *(const half8*)(&thi[cc][ch * 8]);
    *(half8*)(dl + (size_t)cc * 2048 + ch * 8) = *(const half8*)(&tlo[cc][ch * 8]);
  }
}

// ---------------- MFMA GEMM: fp32 A staged + on-the-fly hi/lo split ---------
__global__ __launch_bounds__(256) void gemm_mfma(const float* __restrict__ X,
                                                 const _Float16* __restrict__ WThi,
                                                 const _Float16* __restrict__ WTlo,
                                                 float* __restrict__ partial) {
  // 16x16 supertile swizzle for L2 locality
  const int bid = blockIdx.x;
  const int st = bid >> 8;
  const int stm = st & 3;
  const int stn = st >> 2;
  const int li = bid & 255;
  const int mtile = stm * 16 + (li >> 4);
  const int ntile = stn * 16 + (li & 15);

  const int tid = threadIdx.x;
  const int wave = tid >> 6, lane = tid & 63;
  const int wm = wave >> 1, wn = wave & 1;
  const int h = lane >> 5;

  __shared__ __align__(16) char lds[32768];
  char* ldsA = lds;            // 128 rows x 128B fp32, 8-chunk XOR swizzle
  char* ldsBhi = lds + 16384;  // 128 rows x 64B fp16, 4-chunk XOR swizzle
  char* ldsBlo = lds + 24576;

  // ---- A staging: 4 DMAs/thread, rows wave*32+q*8+lr, chunk cg = cpos^lr
  const int lrA = lane >> 3;   // 0..7
  const int cposA = lane & 7;
  const int cgA = cposA ^ lrA;
  const float* xg[4];
  int ldsAoff[4];
#pragma unroll
  for (int q = 0; q < 4; ++q) {
    const int row = wave * 32 + q * 8 + lrA;
    xg[q] = X + (size_t)(mtile * 128 + row) * 2048 + cgA * 4;
    ldsAoff[q] = (wave * 32 + q * 8) * 128;  // wave-uniform; HW adds lane*16
  }

  // ---- B staging (fp16 hi/lo): as round 4
  const int lrB = lane >> 2;
  const int cposB = lane & 3;
  const int cgB = cposB ^ ((lrB >> 1) & 3);
  const int rB0s = wave * 32 + lrB;
  const int rB1s = rB0s + 16;
  const _Float16* wh0 = WThi + (size_t)(ntile * 128 + rB0s) * 2048 + cgB * 8;
  const _Float16* wh1 = WThi + (size_t)(ntile * 128 + rB1s) * 2048 + cgB * 8;
  const _Float16* wl0 = WTlo + (size_t)(ntile * 128 + rB0s) * 2048 + cgB * 8;
  const _Float16* wl1 = WTlo + (size_t)(ntile * 128 + rB1s) * 2048 + cgB * 8;
  const int lqB0 = wave * 2048;
  const int lqB1 = lqB0 + 1024;

  // ---- A fragment read offsets (fp32): chunks g = s*4+h*2+c, key = lane&7
  const int keyA = lane & 7;
  const int rowA0 = wm * 64 + (lane & 31);
  const int rowA1 = rowA0 + 32;
  int oAf0[2][2], oAf1[2][2];
#pragma unroll
  for (int s = 0; s < 2; ++s)
#pragma unroll
    for (int c = 0; c < 2; ++c) {
      const int g = s * 4 + h * 2 + c;
      oAf0[s][c] = rowA0 * 128 + ((g ^ keyA) << 4);
      oAf1[s][c] = rowA1 * 128 + ((g ^ keyA) << 4);
    }

  // ---- B fragment read offsets (fp16): as round 4
  const int rB0 = wn * 64 + (lane & 31);
  const int rB1 = rB0 + 32;
  auto foffB = [&](int r, int s) {
    return r * 64 + (((s * 2 + h) ^ ((r >> 1) & 3)) << 4);
  };
  const int oB0[2] = {foffB(rB0, 0), foffB(rB0, 1)};
  const int oB1[2] = {foffB(rB1, 0), foffB(rB1, 1)};

  floatx16 acc00 = {}, acc01 = {}, acc10 = {}, acc11 = {};

  auto cvtA = [](const char* p0, const char* p1, half8& ah, half8& al) {
    float4 f0 = *(const float4*)p0;
    float4 f1 = *(const float4*)p1;
    float xf[8] = {f0.x, f0.y, f0.z, f0.w, f1.x, f1.y, f1.z, f1.w};
#pragma unroll
    for (int j = 0; j < 8; ++j) {
      _Float16 hv = (_Float16)xf[j];
      ah[j] = hv;
      al[j] = (_Float16)(xf[j] - (float)hv);
    }
  };

  for (int kt = 0; kt < 64; ++kt) {
    const int k0 = kt * 32;
#pragma unroll
    for (int q = 0; q < 4; ++q) GLL16(xg[q] + k0, ldsA + ldsAoff[q]);
    GLL16(wh0 + k0, ldsBhi + lqB0);
    GLL16(wh1 + k0, ldsBhi + lqB1);
    GLL16(wl0 + k0, ldsBlo + lqB0);
    GLL16(wl1 + k0, ldsBlo + lqB1);
    __syncthreads();
#pragma unroll
    for (int s = 0; s < 2; ++s) {
      half8 ah0, al0, ah1, al1;
      cvtA(ldsA + oAf0[s][0], ldsA + oAf0[s][1], ah0, al0);
      cvtA(ldsA + oAf1[s][0], ldsA + oAf1[s][1], ah1, al1);
      half8 bh0 = *(const half8*)(ldsBhi + oB0[s]);
      half8 bh1 = *(const half8*)(ldsBhi + oB1[s]);
      half8 bl0 = *(const half8*)(ldsBlo + oB0[s]);
      half8 bl1 = *(const half8*)(ldsBlo + oB1[s]);
      acc00 = __builtin_amdgcn_mfma_f32_32x32x16_f16(ah0, bh0, acc00, 0, 0, 0);
      acc00 = __builtin_amdgcn_mfma_f32_32x32x16_f16(ah0, bl0, acc00, 0, 0, 0);
      acc00 = __builtin_amdgcn_mfma_f32_32x32x16_f16(al0, bh0, acc00, 0, 0, 0);
      acc01 = __builtin_amdgcn_mfma_f32_32x32x16_f16(ah0, bh1, acc01, 0, 0, 0);
      acc01 = __builtin_amdgcn_mfma_f32_32x32x16_f16(ah0, bl1, acc01, 0, 0, 0);
      acc01 = __builtin_amdgcn_mfma_f32_32x32x16_f16(al0, bh1, acc01, 0, 0, 0);
      acc10 = __builtin_amdgcn_mfma_f32_32x32x16_f16(ah1, bh0, acc10, 0, 0, 0);
      acc10 = __builtin_amdgcn_mfma_f32_32x32x16_f16(ah1, bl0, acc10, 0, 0, 0);
      acc10 = __builtin_amdgcn_mfma_f32_32x32x16_f16(al1, bh0, acc10, 0, 0, 0);
      acc11 = __builtin_amdgcn_mfma_f32_32x32x16_f16(ah1, bh1, acc11, 0, 0, 0);
      acc11 = __builtin_amdgcn_mfma_f32_32x32x16_f16(ah1, bl1, acc11, 0, 0, 0);
      acc11 = __builtin_amdgcn_mfma_f32_32x32x16_f16(al1, bh1, acc11, 0, 0, 0);
    }
    __syncthreads();
  }

  // epilogue: per-row sum of squares over this wave's 64 cols
  float myv = 0.f;
#pragma unroll
  for (int i = 0; i < 2; ++i) {
    const floatx16& c0 = i ? acc10 : acc00;
    const floatx16& c1 = i ? acc11 : acc01;
#pragma unroll
    for (int reg = 0; reg < 16; ++reg) {
      float v = c0[reg] * c0[reg] + c1[reg] * c1[reg];
#pragma unroll
      for (int m = 1; m <= 16; m <<= 1) v += __shfl_xor(v, m, 64);
      if ((lane & 31) == i * 16 + reg) myv = v;
    }
  }
  {
    const int i = (lane & 31) >> 4;
    const int reg = lane & 15;
    const int row = i * 32 + (reg & 3) + 8 * (reg >> 2) + 4 * h;
    const int token = mtile * 128 + wm * 64 + row;
    const int slice = ntile * 2 + wn;  // e*8+u
    partial[(size_t)token * 64 + slice] = myv;
  }
}

// ---------------- softmax + top-2 per token ---------------------------------
__global__ void route_kernel(const float* __restrict__ partial,
                             int* __restrict__ idx1, int* __restrict__ idx2,
                             float* __restrict__ p1, float* __restrict__ p2) {
  int t = blockIdx.x * blockDim.x + threadIdx.x;
  if (t >= Mm) return;
  float l[Ee];
  float mx = -1e30f;
#pragma unroll
  for (int e = 0; e < Ee; ++e) {
    float s = 0.f;
#pragma unroll
    for (int u = 0; u < 8; ++u) s += partial[(size_t)t * 64 + e * 8 + u];
    l[e] = sqrtf(s);
    mx = fmaxf(mx, l[e]);
  }
  float p[Ee];
  float s = 0.f;
#pragma unroll
  for (int e = 0; e < Ee; ++e) {
    p[e] = expf(l[e] - mx);
    s += p[e];
  }
  float inv = 1.f / s;
  int i1 = 0;
  float b1 = l[0];
#pragma unroll
  for (int e = 1; e < Ee; ++e)
    if (l[e] > b1) { b1 = l[e]; i1 = e; }
  int i2 = -1;
  float b2 = -1e30f;
#pragma unroll
  for (int e = 0; e < Ee; ++e)
    if (e != i1 && l[e] > b2) { b2 = l[e]; i2 = e; }
  idx1[t] = i1;
  idx2[t] = i2;
  p1[t] = p[i1] * inv;
  p2[t] = p[i2] * inv;
}

// ---------------- per-batch capacity priority scan --------------------------
__global__ void scan_kernel(const int* __restrict__ idx1,
                            const int* __restrict__ idx2,
                            int* __restrict__ prios) {
  const int b = blockIdx.x;
  const int tid = threadIdx.x;
  __shared__ int cnts[256][8];
  int cnt[8] = {0, 0, 0, 0, 0, 0, 0, 0};
  int eloc[16];
  const int base_p = tid * 16;
#pragma unroll
  for (int i = 0; i < 16; ++i) {
    int p = base_p + i;
    int k = p >> 11;
    int n = p & (Nn - 1);
    int e = (k == 0 ? idx1 : idx2)[b * Nn + n];
    eloc[i] = e;
    cnt[e]++;
  }
#pragma unroll
  for (int e = 0; e < 8; ++e) cnts[tid][e] = cnt[e];
  __syncthreads();
  if (tid < 8) {
    int run = 0;
    for (int i = 0; i < 256; ++i) {
      int v = cnts[i][tid];
      cnts[i][tid] = run;
      run += v;
    }
  }
  __syncthreads();
  int base[8];
#pragma unroll
  for (int e = 0; e < 8; ++e) base[e] = cnts[tid][e];
#pragma unroll
  for (int i = 0; i < 16; ++i) {
    int e = eloc[i];
    prios[b * 2 * Nn + base_p + i] = base[e]++;
  }
}

// ---------------- zero output ------------------------------------------------
__global__ void zero_kernel(float4* __restrict__ out, int n4) {
  int i = blockIdx.x * blockDim.x + threadIdx.x;
  if (i < n4) out[i] = make_float4(0.f, 0.f, 0.f, 0.f);
}

// ---------------- scatter dispatch/combine ----------------------------------
__global__ void scatter_kernel(const int* __restrict__ idx1,
                               const int* __restrict__ idx2,
                               const float* __restrict__ p1,
                               const float* __restrict__ p2,
                               const int* __restrict__ prios,
                               float* __restrict__ out, int cap) {
  int t = blockIdx.x * blockDim.x + threadIdx.x;
  if (t >= Mm) return;
  int b = t >> 11;
  int n = t & (Nn - 1);
  size_t disp = (size_t)t * Ee * cap;
  size_t comb = disp + (size_t)Mm * Ee * cap;
  {
    int e = idx1[t];
    int p = prios[b * 2 * Nn + n];
    if (p < cap) {
      out[disp + (size_t)e * cap + p] = 1.f;
      out[comb + (size_t)e * cap + p] = p1[t];
    }
  }
  {
    int e = idx2[t];
    int p = prios[b * 2 * Nn + Nn + n];
    if (p < cap) {
      out[disp + (size_t)e * cap + p] = 1.f;
      out[comb + (size_t)e * cap + p] = p2[t];
    }
  }
}

extern "C" void kernel_launch(void* const* d_in, const int* in_sizes, int n_in,
                              void* d_out, int out_size, void* d_ws, size_t ws_size,
                              hipStream_t stream) {
  const float* X = (const float*)d_in[0];
  const float* W = (const float*)d_in[1];
  float* out = (float*)d_out;
  const int cap = out_size / (2 * Bb * Nn * Ee);  // 640

  char* ws = (char*)d_ws;
  _Float16* WThi = (_Float16*)ws;                  // 16 MB
  _Float16* WTlo = (_Float16*)(ws + 16777216ull);  // 16 MB
  float* partial = (float*)(ws + 33554432ull);     // Mm*64 f32 = 2 MB
  int* idx1 = (int*)(ws + 35651584ull);
  int* idx2 = idx1 + Mm;
  float* p1 = (float*)(idx2 + Mm);
  float* p2 = p1 + Mm;
  int* prios = (int*)(p2 + Mm);

  transpose_w<<<dim3(32, 8, 8), 256, 0, stream>>>(W, WThi, WTlo);
  gemm_mfma<<<2048, 256, 0, stream>>>(X, WThi, WTlo, partial);
  route_kernel<<<Mm / 256, 256, 0, stream>>>(partial, idx1, idx2, p1, p2);
  scan_kernel<<<Bb, 256, 0, stream>>>(idx1, idx2, prios);
  const int n4 = out_size / 4;
  zero_kernel<<<(n4 + 255) / 256, 256, 0, stream>>>((float4*)out, n4);
  scatter_kernel<<<Mm / 256, 256, 0, stream>>>(idx1, idx2, p1, p2, prios, out, cap);
}